// Round 4
// baseline (1027.956 us; speedup 1.0000x reference)
//
#include <hip/hip_runtime.h>

#define NN 100000
#define NE 3200000
#define HM 30
#define HG 10
#define MAXK 26
#define OVF_CAP 8192

// ---- fused layer, scalar (SGPR) weights, 2 edges per thread:
// each s_load-ed weight feeds 2 FMAs; two independent acc streams
// break the 30-deep dependent FMA chain of the 1-edge version.
template<int NIN>
__device__ __forceinline__ void layer_relu_g2(const float* __restrict__ W,
                                              const float* __restrict__ b,
                                              const float* __restrict__ inA,
                                              const float* __restrict__ inB,
                                              float* __restrict__ outA,
                                              float* __restrict__ outB) {
    float accA[HM], accB[HM];
    #pragma unroll
    for (int j = 0; j < HM; j++) { accA[j] = b[j]; accB[j] = b[j]; }
    #pragma unroll
    for (int i = 0; i < NIN; i++) {
        float va = inA[i];
        float vb = inB[i];
        #pragma unroll
        for (int j = 0; j < HM; j++) {
            float w = W[i * HM + j];
            accA[j] = fmaf(va, w, accA[j]);
            accB[j] = fmaf(vb, w, accB[j]);
        }
    }
    #pragma unroll
    for (int j = 0; j < HM; j++) {
        outA[j] = fmaxf(accA[j], 0.f);
        outB[j] = fmaxf(accB[j], 0.f);
    }
}

// Epilogue for one edge: gumbel-argmax, sigmoid edge weight, slot/overflow write.
__device__ __forceinline__ void finish_edge(
    int e, int s, int t, float l0, float l1,
    const float* __restrict__ gum, const float* __restrict__ ee,
    float wl, float blv,
    float2* __restrict__ slots, int* __restrict__ cnt,
    int* __restrict__ ohead, int* __restrict__ onxt,
    float* __restrict__ ovf_w, int* __restrict__ ovf_s, int* __restrict__ novf)
{
    const float2 g2 = ((const float2*)gum)[e];
    float v0 = l0 + g2.x;
    float v1 = l1 + g2.y;

    // forward: edge_value = (v1 > v0) ? 1 : 0; active iff edge_value == 0
    float ew = 0.f;
    if (!(v1 > v0)) {
        const float2 e2 = ((const float2*)ee)[e];
        float z = fmaf(e2.x, wl, blv);
        ew = e2.y / (1.f + __expf(-z));
    }
    if (ew != 0.f) {
        int slot = atomicAdd(&cnt[t], 1);
        if (slot < MAXK) {
            slots[(size_t)t * MAXK + slot] = make_float2(ew, __int_as_float(s));
        } else {
            int i = atomicAdd(novf, 1);
            if (i < OVF_CAP) {
                ovf_w[i] = ew;
                ovf_s[i] = s;
                onxt[i] = atomicExch(&ohead[t], i);
            }
        }
    }
}

// ---------------- Stage 0: pack node features + xw ----------------
__global__ __launch_bounds__(256) void pack_kernel(
    const float* __restrict__ x, const float* __restrict__ token,
    const float* __restrict__ Wc,
    float* __restrict__ xall8, float* __restrict__ xwp)
{
    __shared__ float sWc[6 * HG];
    if (threadIdx.x < 6 * HG) sWc[threadIdx.x] = Wc[threadIdx.x];
    __syncthreads();

    int n = blockIdx.x * 256 + threadIdx.x;
    if (n >= NN) return;

    float xa[6];
    xa[0] = x[n];
    #pragma unroll
    for (int i = 0; i < 5; i++) xa[1 + i] = token[n * 5 + i];

    float4* x4 = (float4*)xall8;
    x4[n * 2 + 0] = make_float4(xa[0], xa[1], xa[2], xa[3]);
    x4[n * 2 + 1] = make_float4(xa[4], xa[5], 0.f, 0.f);

    float w[12];
    #pragma unroll
    for (int k = 0; k < HG; k++) {
        float a = 0.f;
        #pragma unroll
        for (int i = 0; i < 6; i++) a = fmaf(xa[i], sWc[i * HG + k], a);
        w[k] = a;
    }
    w[10] = 0.f; w[11] = 0.f;
    float4* wp = (float4*)(xwp + (size_t)n * 12);
    wp[0] = make_float4(w[0], w[1], w[2], w[3]);
    wp[1] = make_float4(w[4], w[5], w[6], w[7]);
    wp[2] = make_float4(w[8], w[9], w[10], w[11]);
}

// ---------------- Stage 1: per-edge MLP (scalar weights, 2 edges/thread) ----
__global__ __launch_bounds__(256) void edge_mlp4_kernel(
    const float* __restrict__ xall8,
    const float* __restrict__ eg, const float* __restrict__ ee,
    const float* __restrict__ gum, const int* __restrict__ eidx,
    const float* __restrict__ W0, const float* __restrict__ b0,
    const float* __restrict__ W1, const float* __restrict__ b1,
    const float* __restrict__ W2, const float* __restrict__ b2,
    const float* __restrict__ W3, const float* __restrict__ b3,
    const float* __restrict__ Wl, const float* __restrict__ bl,
    float2* __restrict__ slots, int* __restrict__ cnt,
    int* __restrict__ ohead, int* __restrict__ onxt,
    float* __restrict__ ovf_w, int* __restrict__ ovf_s, int* __restrict__ novf)
{
    // block covers 512 consecutive edges in two coalesced 256-wide chunks
    int base = blockIdx.x * 512;                 // NE == 6250*512 exactly
    int eA = base + threadIdx.x;
    int eB = base + 256 + threadIdx.x;

    int sA = eidx[eA];
    int tA = eidx[NE + eA];
    int sB = eidx[eB];
    int tB = eidx[NE + eB];

    const float4* x4 = (const float4*)xall8;
    float efA[13], efB[13];
    {
        float4 qa = x4[sA * 2], qb = x4[sA * 2 + 1];
        float4 qc = x4[tA * 2], qd = x4[tA * 2 + 1];
        efA[0] = qa.x; efA[1] = qa.y; efA[2] = qa.z; efA[3] = qa.w;
        efA[4] = qb.x; efA[5] = qb.y;
        efA[6] = qc.x; efA[7] = qc.y; efA[8] = qc.z; efA[9] = qc.w;
        efA[10] = qd.x; efA[11] = qd.y; efA[12] = eg[eA];
    }
    {
        float4 qa = x4[sB * 2], qb = x4[sB * 2 + 1];
        float4 qc = x4[tB * 2], qd = x4[tB * 2 + 1];
        efB[0] = qa.x; efB[1] = qa.y; efB[2] = qa.z; efB[3] = qa.w;
        efB[4] = qb.x; efB[5] = qb.y;
        efB[6] = qc.x; efB[7] = qc.y; efB[8] = qc.z; efB[9] = qc.w;
        efB[10] = qd.x; efB[11] = qd.y; efB[12] = eg[eB];
    }

    float hA[HM], hB[HM], gA[HM], gB[HM];
    layer_relu_g2<13>(W0, b0, efA, efB, hA, hB);
    layer_relu_g2<HM>(W1, b1, hA, hB, gA, gB);
    layer_relu_g2<HM>(W2, b2, gA, gB, hA, hB);

    float l0A = b3[0], l1A = b3[1];
    float l0B = l0A, l1B = l1A;
    #pragma unroll
    for (int i = 0; i < HM; i++) {
        float w0 = W3[i * 2 + 0];
        float w1 = W3[i * 2 + 1];
        l0A = fmaf(hA[i], w0, l0A);
        l1A = fmaf(hA[i], w1, l1A);
        l0B = fmaf(hB[i], w0, l0B);
        l1B = fmaf(hB[i], w1, l1B);
    }

    float wl = Wl[0], blv = bl[0];
    finish_edge(eA, sA, tA, l0A, l1A, gum, ee, wl, blv,
                slots, cnt, ohead, onxt, ovf_w, ovf_s, novf);
    finish_edge(eB, sB, tB, l0B, l1B, gum, ee, wl, blv,
                slots, cnt, ohead, onxt, ovf_w, ovf_s, novf);
}

// ---------------- Stage 2: per-node deg -> dis; scale xwp in place to z ----
__global__ __launch_bounds__(256) void node_deg_kernel(
    const float2* __restrict__ slots, const int* __restrict__ cnt,
    const int* __restrict__ ohead, const int* __restrict__ onxt,
    const float* __restrict__ ovf_w,
    float* __restrict__ xwp, float* __restrict__ dis)
{
    int n = blockIdx.x * 256 + threadIdx.x;
    if (n >= NN) return;

    int c = cnt[n];
    int cc = c < MAXK ? c : MAXK;
    float deg = 0.f;
    for (int j = 0; j < cc; j++) deg += slots[(size_t)n * MAXK + j].x;
    for (int i = ohead[n]; i >= 0; i = onxt[i]) deg += ovf_w[i];

    float d = rsqrtf(deg + 1.0f);   // +1 = self loop
    dis[n] = d;

    float4* wp = (float4*)(xwp + (size_t)n * 12);
    #pragma unroll
    for (int q = 0; q < 3; q++) {
        float4 v = wp[q];
        v.x *= d; v.y *= d; v.z *= d; v.w *= d;
        wp[q] = v;
    }
}

// ---------------- Stage 3: per-node gather + epilogue (no atomics) ----------
__global__ __launch_bounds__(256) void gather_out2_kernel(
    const float2* __restrict__ slots, const int* __restrict__ cnt,
    const int* __restrict__ ohead, const int* __restrict__ onxt,
    const float* __restrict__ ovf_w, const int* __restrict__ ovf_s,
    const float* __restrict__ z, const float* __restrict__ dis,
    const float* __restrict__ bc, const float* __restrict__ Wo,
    const float* __restrict__ bo, float* __restrict__ out)
{
    __shared__ float sbc[12], sWo[12], sbo;
    if (threadIdx.x < 12) {
        sbc[threadIdx.x] = (threadIdx.x < HG) ? bc[threadIdx.x] : 0.f;
        sWo[threadIdx.x] = (threadIdx.x < HG) ? Wo[threadIdx.x] : 0.f;
    }
    if (threadIdx.x == 0) sbo = bo[0];
    __syncthreads();

    int n = blockIdx.x * 256 + threadIdx.x;
    if (n >= NN) return;

    const float4* Z = (const float4*)z;
    float4 A0 = make_float4(0.f, 0.f, 0.f, 0.f), A1 = A0, A2 = A0;

    int c = cnt[n];
    int cc = c < MAXK ? c : MAXK;
    for (int j = 0; j < cc; j++) {
        float2 p = slots[(size_t)n * MAXK + j];
        float w = p.x;
        int s = __float_as_int(p.y);
        float4 z0 = Z[s * 3], z1 = Z[s * 3 + 1], z2 = Z[s * 3 + 2];
        A0.x = fmaf(w, z0.x, A0.x); A0.y = fmaf(w, z0.y, A0.y);
        A0.z = fmaf(w, z0.z, A0.z); A0.w = fmaf(w, z0.w, A0.w);
        A1.x = fmaf(w, z1.x, A1.x); A1.y = fmaf(w, z1.y, A1.y);
        A1.z = fmaf(w, z1.z, A1.z); A1.w = fmaf(w, z1.w, A1.w);
        A2.x = fmaf(w, z2.x, A2.x); A2.y = fmaf(w, z2.y, A2.y);
    }
    for (int i = ohead[n]; i >= 0; i = onxt[i]) {
        float w = ovf_w[i];
        int s = ovf_s[i];
        float4 z0 = Z[s * 3], z1 = Z[s * 3 + 1], z2 = Z[s * 3 + 2];
        A0.x = fmaf(w, z0.x, A0.x); A0.y = fmaf(w, z0.y, A0.y);
        A0.z = fmaf(w, z0.z, A0.z); A0.w = fmaf(w, z0.w, A0.w);
        A1.x = fmaf(w, z1.x, A1.x); A1.y = fmaf(w, z1.y, A1.y);
        A1.z = fmaf(w, z1.z, A1.z); A1.w = fmaf(w, z1.w, A1.w);
        A2.x = fmaf(w, z2.x, A2.x); A2.y = fmaf(w, z2.y, A2.y);
    }

    // self loop: + z[n] (w=1), then everything * dis[n], + bc
    float4 s0 = Z[n * 3], s1 = Z[n * 3 + 1], s2 = Z[n * 3 + 2];
    A0.x += s0.x; A0.y += s0.y; A0.z += s0.z; A0.w += s0.w;
    A1.x += s1.x; A1.y += s1.y; A1.z += s1.z; A1.w += s1.w;
    A2.x += s2.x; A2.y += s2.y;

    float d = dis[n];
    float v[10] = { A0.x, A0.y, A0.z, A0.w, A1.x, A1.y, A1.z, A1.w, A2.x, A2.y };
    float o = sbo;
    #pragma unroll
    for (int k = 0; k < HG; k++)
        o = fmaf(fmaf(v[k], d, sbc[k]), sWo[k], o);
    out[n] = 1.f / (1.f + __expf(-o));
}

// ================= Fallback path (Round-1 scatter) =================
__global__ __launch_bounds__(256) void edge_mlp_kernel(
    const float* __restrict__ x, const float* __restrict__ token,
    const float* __restrict__ eg, const float* __restrict__ ee,
    const float* __restrict__ gum, const int* __restrict__ eidx,
    const float* __restrict__ W0, const float* __restrict__ b0,
    const float* __restrict__ W1, const float* __restrict__ b1,
    const float* __restrict__ W2, const float* __restrict__ b2,
    const float* __restrict__ W3, const float* __restrict__ b3,
    const float* __restrict__ Wl, const float* __restrict__ bl,
    float* __restrict__ ew_out, float* __restrict__ deg)
{
    __shared__ float sW0[13 * HM];
    __shared__ float sW1[HM * HM];
    __shared__ float sW2[HM * HM];
    __shared__ float sW3f[HM * 2];
    __shared__ float sb0[HM], sb1[HM], sb2[HM], sb3[2];
    __shared__ float sWl, sbl;

    for (int i = threadIdx.x; i < 13 * HM; i += 256) sW0[i] = W0[i];
    for (int i = threadIdx.x; i < HM * HM; i += 256) sW1[i] = W1[i];
    for (int i = threadIdx.x; i < HM * HM; i += 256) sW2[i] = W2[i];
    for (int i = threadIdx.x; i < HM * 2; i += 256) sW3f[i] = W3[i];
    if (threadIdx.x < HM) {
        sb0[threadIdx.x] = b0[threadIdx.x];
        sb1[threadIdx.x] = b1[threadIdx.x];
        sb2[threadIdx.x] = b2[threadIdx.x];
    }
    if (threadIdx.x < 2) sb3[threadIdx.x] = b3[threadIdx.x];
    if (threadIdx.x == 0) { sWl = Wl[0]; sbl = bl[0]; }
    __syncthreads();

    int e = blockIdx.x * 256 + threadIdx.x;
    if (e >= NE) return;
    int s = eidx[e];
    int t = eidx[NE + e];

    float ef[13];
    ef[0] = x[s];
    #pragma unroll
    for (int i = 0; i < 5; i++) ef[1 + i] = token[s * 5 + i];
    ef[6] = x[t];
    #pragma unroll
    for (int i = 0; i < 5; i++) ef[7 + i] = token[t * 5 + i];
    ef[12] = eg[e];

    float h[HM], h2[HM];
    #pragma unroll
    for (int j = 0; j < HM; j++) {
        float a = sb0[j];
        #pragma unroll
        for (int i = 0; i < 13; i++) a = fmaf(ef[i], sW0[i * HM + j], a);
        h[j] = a > 0.f ? a : 0.f;
    }
    #pragma unroll
    for (int j = 0; j < HM; j++) {
        float a = sb1[j];
        #pragma unroll
        for (int i = 0; i < HM; i++) a = fmaf(h[i], sW1[i * HM + j], a);
        h2[j] = a > 0.f ? a : 0.f;
    }
    #pragma unroll
    for (int j = 0; j < HM; j++) {
        float a = sb2[j];
        #pragma unroll
        for (int i = 0; i < HM; i++) a = fmaf(h2[i], sW2[i * HM + j], a);
        h[j] = a > 0.f ? a : 0.f;
    }
    float l0 = sb3[0], l1 = sb3[1];
    #pragma unroll
    for (int i = 0; i < HM; i++) {
        l0 = fmaf(h[i], sW3f[i * 2 + 0], l0);
        l1 = fmaf(h[i], sW3f[i * 2 + 1], l1);
    }
    const float2 g2 = ((const float2*)gum)[e];
    float v0 = l0 + g2.x, v1 = l1 + g2.y;
    float ew = 0.f;
    if (!(v1 > v0)) {
        const float2 ee2 = ((const float2*)ee)[e];
        float z = fmaf(ee2.x, sWl, sbl);
        ew = ee2.y / (1.f + __expf(-z));
    }
    ew_out[e] = ew;
    if (ew != 0.f) atomicAdd(&deg[t], ew);
}

__global__ __launch_bounds__(256) void node_pre_kernel(
    const float* __restrict__ x, const float* __restrict__ token,
    const float* __restrict__ Wc, const float* __restrict__ deg,
    float* __restrict__ xw, float* __restrict__ dis)
{
    __shared__ float sWc[6 * HG];
    if (threadIdx.x < 6 * HG) sWc[threadIdx.x] = Wc[threadIdx.x];
    __syncthreads();
    int n = blockIdx.x * 256 + threadIdx.x;
    if (n >= NN) return;
    float xa[6];
    xa[0] = x[n];
    #pragma unroll
    for (int i = 0; i < 5; i++) xa[1 + i] = token[n * 5 + i];
    #pragma unroll
    for (int k = 0; k < HG; k++) {
        float a = 0.f;
        #pragma unroll
        for (int i = 0; i < 6; i++) a = fmaf(xa[i], sWc[i * HG + k], a);
        xw[n * HG + k] = a;
    }
    dis[n] = rsqrtf(deg[n] + 1.0f);
}

__global__ __launch_bounds__(256) void edge_scatter_kernel(
    const int* __restrict__ eidx, const float* __restrict__ ew,
    const float* __restrict__ dis, const float* __restrict__ xw,
    float* __restrict__ agg)
{
    int e = blockIdx.x * 256 + threadIdx.x;
    if (e >= NE) return;
    float w = ew[e];
    if (w == 0.f) return;
    int s = eidx[e];
    int t = eidx[NE + e];
    float norm = dis[s] * w * dis[t];
    #pragma unroll
    for (int k = 0; k < HG; k++)
        atomicAdd(&agg[t * HG + k], norm * xw[s * HG + k]);
}

__global__ __launch_bounds__(256) void node_out_kernel(
    const float* __restrict__ agg, const float* __restrict__ xw,
    const float* __restrict__ dis, const float* __restrict__ bc,
    const float* __restrict__ Wo, const float* __restrict__ bo,
    float* __restrict__ out)
{
    __shared__ float sbc[HG], sWo[HG], sbo;
    if (threadIdx.x < HG) { sbc[threadIdx.x] = bc[threadIdx.x]; sWo[threadIdx.x] = Wo[threadIdx.x]; }
    if (threadIdx.x == 0) sbo = bo[0];
    __syncthreads();
    int n = blockIdx.x * 256 + threadIdx.x;
    if (n >= NN) return;
    float d = dis[n];
    float self = d * d;
    float acc = sbo;
    #pragma unroll
    for (int k = 0; k < HG; k++) {
        float v = agg[n * HG + k] + xw[n * HG + k] * self + sbc[k];
        acc = fmaf(v, sWo[k], acc);
    }
    out[n] = 1.f / (1.f + __expf(-acc));
}

extern "C" void kernel_launch(void* const* d_in, const int* in_sizes, int n_in,
                              void* d_out, int out_size, void* d_ws, size_t ws_size,
                              hipStream_t stream) {
    const float* x   = (const float*)d_in[0];
    const float* tok = (const float*)d_in[1];
    const float* eg  = (const float*)d_in[2];
    const float* ee  = (const float*)d_in[3];
    const float* gum = (const float*)d_in[4];
    const int*   ei  = (const int*)d_in[5];
    const float* W0  = (const float*)d_in[6];
    const float* b0  = (const float*)d_in[7];
    const float* W1  = (const float*)d_in[8];
    const float* b1  = (const float*)d_in[9];
    const float* W2  = (const float*)d_in[10];
    const float* b2  = (const float*)d_in[11];
    const float* W3  = (const float*)d_in[12];
    const float* b3  = (const float*)d_in[13];
    const float* Wl  = (const float*)d_in[14];
    const float* bl  = (const float*)d_in[15];
    const float* Wc  = (const float*)d_in[16];
    const float* bc  = (const float*)d_in[17];
    const float* Wo  = (const float*)d_in[18];
    const float* bo  = (const float*)d_in[19];
    float* out = (float*)d_out;

    dim3 blk(256);
    dim3 egrid2(NE / 512);              // exact: 6250 (2 edges/thread)
    dim3 egrid(NE / 256);               // exact: 12500 (fallback)
    dim3 ngrid((NN + 255) / 256);

    // New-path ws layout (float offsets)
    size_t off_xall8 = 0;                              // NN*8
    size_t off_xwp   = off_xall8 + (size_t)NN * 8;     // NN*12
    size_t off_slots = off_xwp + (size_t)NN * 12;      // NN*MAXK*2
    size_t off_cnt   = off_slots + (size_t)NN * MAXK * 2; // NN int
    size_t off_novf  = off_cnt + NN;                   // 1 int
    size_t off_dis   = off_novf + 1;                   // NN
    size_t off_ohead = off_dis + NN;                   // NN int
    size_t off_ovfw  = off_ohead + NN;                 // OVF_CAP
    size_t off_ovfs  = off_ovfw + OVF_CAP;             // OVF_CAP int
    size_t off_onxt  = off_ovfs + OVF_CAP;             // OVF_CAP int
    size_t need_new  = (off_onxt + OVF_CAP) * sizeof(float);

    if (ws_size >= need_new) {
        float*  ws    = (float*)d_ws;
        float*  xall8 = ws + off_xall8;
        float*  xwp   = ws + off_xwp;
        float2* slots = (float2*)(ws + off_slots);
        int*    cnt   = (int*)(ws + off_cnt);
        int*    novf  = (int*)(ws + off_novf);
        float*  dis   = ws + off_dis;
        int*    ohead = (int*)(ws + off_ohead);
        float*  ovf_w = ws + off_ovfw;
        int*    ovf_s = (int*)(ws + off_ovfs);
        int*    onxt  = (int*)(ws + off_onxt);

        hipMemsetAsync(cnt, 0, (size_t)(NN + 1) * sizeof(int), stream);   // cnt + novf
        hipMemsetAsync(ohead, 0xFF, (size_t)NN * sizeof(int), stream);    // ohead = -1

        pack_kernel<<<ngrid, blk, 0, stream>>>(x, tok, Wc, xall8, xwp);
        edge_mlp4_kernel<<<egrid2, blk, 0, stream>>>(xall8, eg, ee, gum, ei,
                                                     W0, b0, W1, b1, W2, b2, W3, b3,
                                                     Wl, bl, slots, cnt,
                                                     ohead, onxt, ovf_w, ovf_s, novf);
        node_deg_kernel<<<ngrid, blk, 0, stream>>>(slots, cnt, ohead, onxt, ovf_w,
                                                   xwp, dis);
        gather_out2_kernel<<<ngrid, blk, 0, stream>>>(slots, cnt, ohead, onxt,
                                                      ovf_w, ovf_s, xwp, dis,
                                                      bc, Wo, bo, out);
    } else {
        // Fallback: Round-1 scatter layout: [ew: NE][deg: NN][agg: NN*HG][xw: NN*HG][dis: NN]
        float* ws  = (float*)d_ws;
        float* ew  = ws;
        float* deg = ew + NE;
        float* agg = deg + NN;
        float* xw  = agg + (size_t)NN * HG;
        float* dis = xw + (size_t)NN * HG;

        hipMemsetAsync(deg, 0, (size_t)(NN + (size_t)NN * HG) * sizeof(float), stream);
        edge_mlp_kernel<<<egrid, blk, 0, stream>>>(x, tok, eg, ee, gum, ei,
                                                   W0, b0, W1, b1, W2, b2, W3, b3,
                                                   Wl, bl, ew, deg);
        node_pre_kernel<<<ngrid, blk, 0, stream>>>(x, tok, Wc, deg, xw, dis);
        edge_scatter_kernel<<<egrid, blk, 0, stream>>>(ei, ew, dis, xw, agg);
        node_out_kernel<<<ngrid, blk, 0, stream>>>(agg, xw, dis, bc, Wo, bo, out);
    }
}

// Round 5
// 415.064 us; speedup vs baseline: 2.4766x; 2.4766x over previous
//
#include <hip/hip_runtime.h>

#define NN 100000
#define NE 3200000
#define HM 30
#define HG 10
#define MAXK 26
#define OVF_CAP 8192

// ---------------- Stage -1: transpose+pad weights into ws ----------------
// W0T[30][16] (rows 64B-aligned), W1T/W2T[30][32] (rows 128B-aligned).
// j-outer MLP then reads each output's weights as CONSECUTIVE floats ->
// batched s_load_dwordx8/x16 instead of ~2700 strided s_load_dword.
__global__ __launch_bounds__(256) void wtrans_kernel(
    const float* __restrict__ W0, const float* __restrict__ W1,
    const float* __restrict__ W2,
    float* __restrict__ W0T, float* __restrict__ W1T, float* __restrict__ W2T)
{
    for (int idx = threadIdx.x; idx < HM * 13; idx += 256) {
        int j = idx / 13, i = idx % 13;
        W0T[j * 16 + i] = W0[i * HM + j];
    }
    for (int idx = threadIdx.x; idx < HM * HM; idx += 256) {
        int j = idx / HM, i = idx % HM;
        W1T[j * 32 + i] = W1[i * HM + j];
        W2T[j * 32 + i] = W2[i * HM + j];
    }
}

// ---------------- Stage 0: pack node features + xw ----------------
__global__ __launch_bounds__(256) void pack_kernel(
    const float* __restrict__ x, const float* __restrict__ token,
    const float* __restrict__ Wc,
    float* __restrict__ xall8, float* __restrict__ xwp)
{
    __shared__ float sWc[6 * HG];
    if (threadIdx.x < 6 * HG) sWc[threadIdx.x] = Wc[threadIdx.x];
    __syncthreads();

    int n = blockIdx.x * 256 + threadIdx.x;
    if (n >= NN) return;

    float xa[6];
    xa[0] = x[n];
    #pragma unroll
    for (int i = 0; i < 5; i++) xa[1 + i] = token[n * 5 + i];

    float4* x4 = (float4*)xall8;
    x4[n * 2 + 0] = make_float4(xa[0], xa[1], xa[2], xa[3]);
    x4[n * 2 + 1] = make_float4(xa[4], xa[5], 0.f, 0.f);

    float w[12];
    #pragma unroll
    for (int k = 0; k < HG; k++) {
        float a = 0.f;
        #pragma unroll
        for (int i = 0; i < 6; i++) a = fmaf(xa[i], sWc[i * HG + k], a);
        w[k] = a;
    }
    w[10] = 0.f; w[11] = 0.f;
    float4* wp = (float4*)(xwp + (size_t)n * 12);
    wp[0] = make_float4(w[0], w[1], w[2], w[3]);
    wp[1] = make_float4(w[4], w[5], w[6], w[7]);
    wp[2] = make_float4(w[8], w[9], w[10], w[11]);
}

// ---------------- Stage 1: per-edge MLP, transposed scalar weights ----------
// Same low-pressure j-outer shape the compiler chose for round 3 (VGPR~36,
// no AGPR churn), but weights consecutive per output -> few s_loads.
__global__ __launch_bounds__(256) void edge_mlp5_kernel(
    const float* __restrict__ xall8,
    const float* __restrict__ eg, const float* __restrict__ ee,
    const float* __restrict__ gum, const int* __restrict__ eidx,
    const float* __restrict__ W0T, const float* __restrict__ b0,
    const float* __restrict__ W1T, const float* __restrict__ b1,
    const float* __restrict__ W2T, const float* __restrict__ b2,
    const float* __restrict__ W3, const float* __restrict__ b3,
    const float* __restrict__ Wl, const float* __restrict__ bl,
    float2* __restrict__ slots, int* __restrict__ cnt,
    int* __restrict__ ohead, int* __restrict__ onxt,
    float* __restrict__ ovf_w, int* __restrict__ ovf_s, int* __restrict__ novf)
{
    int e = blockIdx.x * 256 + threadIdx.x;   // NE == 12500*256 exactly
    int s = eidx[e];
    int t = eidx[NE + e];

    const float4* x4 = (const float4*)xall8;
    float4 qa = x4[s * 2], qb = x4[s * 2 + 1];
    float4 qc = x4[t * 2], qd = x4[t * 2 + 1];
    float ef[13] = { qa.x, qa.y, qa.z, qa.w, qb.x, qb.y,
                     qc.x, qc.y, qc.z, qc.w, qd.x, qd.y, eg[e] };

    float h[HM], g[HM];
    #pragma unroll
    for (int j = 0; j < HM; j++) {
        float a = b0[j];
        #pragma unroll
        for (int i = 0; i < 13; i++) a = fmaf(ef[i], W0T[j * 16 + i], a);
        h[j] = fmaxf(a, 0.f);
    }
    #pragma unroll
    for (int j = 0; j < HM; j++) {
        float a = b1[j];
        #pragma unroll
        for (int i = 0; i < HM; i++) a = fmaf(h[i], W1T[j * 32 + i], a);
        g[j] = fmaxf(a, 0.f);
    }
    #pragma unroll
    for (int j = 0; j < HM; j++) {
        float a = b2[j];
        #pragma unroll
        for (int i = 0; i < HM; i++) a = fmaf(g[i], W2T[j * 32 + i], a);
        h[j] = fmaxf(a, 0.f);
    }

    float l0 = b3[0], l1 = b3[1];
    #pragma unroll
    for (int i = 0; i < HM; i++) {
        l0 = fmaf(h[i], W3[i * 2 + 0], l0);
        l1 = fmaf(h[i], W3[i * 2 + 1], l1);
    }

    const float2 g2 = ((const float2*)gum)[e];
    float v0 = l0 + g2.x;
    float v1 = l1 + g2.y;

    // forward: edge_value = (v1 > v0) ? 1 : 0; active iff edge_value == 0
    float ew = 0.f;
    if (!(v1 > v0)) {
        const float2 e2 = ((const float2*)ee)[e];
        float z = fmaf(e2.x, Wl[0], bl[0]);
        ew = e2.y / (1.f + __expf(-z));
    }
    if (ew != 0.f) {
        int slot = atomicAdd(&cnt[t], 1);
        if (slot < MAXK) {
            slots[(size_t)t * MAXK + slot] = make_float2(ew, __int_as_float(s));
        } else {
            int i = atomicAdd(novf, 1);
            if (i < OVF_CAP) {
                ovf_w[i] = ew;
                ovf_s[i] = s;
                onxt[i] = atomicExch(&ohead[t], i);
            }
        }
    }
}

// ---------------- Stage 2: per-node deg -> dis; scale xwp in place to z ----
__global__ __launch_bounds__(256) void node_deg_kernel(
    const float2* __restrict__ slots, const int* __restrict__ cnt,
    const int* __restrict__ ohead, const int* __restrict__ onxt,
    const float* __restrict__ ovf_w,
    float* __restrict__ xwp, float* __restrict__ dis)
{
    int n = blockIdx.x * 256 + threadIdx.x;
    if (n >= NN) return;

    int c = cnt[n];
    int cc = c < MAXK ? c : MAXK;
    float deg = 0.f;
    for (int j = 0; j < cc; j++) deg += slots[(size_t)n * MAXK + j].x;
    for (int i = ohead[n]; i >= 0; i = onxt[i]) deg += ovf_w[i];

    float d = rsqrtf(deg + 1.0f);   // +1 = self loop
    dis[n] = d;

    float4* wp = (float4*)(xwp + (size_t)n * 12);
    #pragma unroll
    for (int q = 0; q < 3; q++) {
        float4 v = wp[q];
        v.x *= d; v.y *= d; v.z *= d; v.w *= d;
        wp[q] = v;
    }
}

// ---------------- Stage 3: per-node gather + epilogue (no atomics) ----------
__global__ __launch_bounds__(256) void gather_out2_kernel(
    const float2* __restrict__ slots, const int* __restrict__ cnt,
    const int* __restrict__ ohead, const int* __restrict__ onxt,
    const float* __restrict__ ovf_w, const int* __restrict__ ovf_s,
    const float* __restrict__ z, const float* __restrict__ dis,
    const float* __restrict__ bc, const float* __restrict__ Wo,
    const float* __restrict__ bo, float* __restrict__ out)
{
    __shared__ float sbc[12], sWo[12], sbo;
    if (threadIdx.x < 12) {
        sbc[threadIdx.x] = (threadIdx.x < HG) ? bc[threadIdx.x] : 0.f;
        sWo[threadIdx.x] = (threadIdx.x < HG) ? Wo[threadIdx.x] : 0.f;
    }
    if (threadIdx.x == 0) sbo = bo[0];
    __syncthreads();

    int n = blockIdx.x * 256 + threadIdx.x;
    if (n >= NN) return;

    const float4* Z = (const float4*)z;
    float4 A0 = make_float4(0.f, 0.f, 0.f, 0.f), A1 = A0, A2 = A0;

    int c = cnt[n];
    int cc = c < MAXK ? c : MAXK;
    for (int j = 0; j < cc; j++) {
        float2 p = slots[(size_t)n * MAXK + j];
        float w = p.x;
        int s = __float_as_int(p.y);
        float4 z0 = Z[s * 3], z1 = Z[s * 3 + 1], z2 = Z[s * 3 + 2];
        A0.x = fmaf(w, z0.x, A0.x); A0.y = fmaf(w, z0.y, A0.y);
        A0.z = fmaf(w, z0.z, A0.z); A0.w = fmaf(w, z0.w, A0.w);
        A1.x = fmaf(w, z1.x, A1.x); A1.y = fmaf(w, z1.y, A1.y);
        A1.z = fmaf(w, z1.z, A1.z); A1.w = fmaf(w, z1.w, A1.w);
        A2.x = fmaf(w, z2.x, A2.x); A2.y = fmaf(w, z2.y, A2.y);
    }
    for (int i = ohead[n]; i >= 0; i = onxt[i]) {
        float w = ovf_w[i];
        int s = ovf_s[i];
        float4 z0 = Z[s * 3], z1 = Z[s * 3 + 1], z2 = Z[s * 3 + 2];
        A0.x = fmaf(w, z0.x, A0.x); A0.y = fmaf(w, z0.y, A0.y);
        A0.z = fmaf(w, z0.z, A0.z); A0.w = fmaf(w, z0.w, A0.w);
        A1.x = fmaf(w, z1.x, A1.x); A1.y = fmaf(w, z1.y, A1.y);
        A1.z = fmaf(w, z1.z, A1.z); A1.w = fmaf(w, z1.w, A1.w);
        A2.x = fmaf(w, z2.x, A2.x); A2.y = fmaf(w, z2.y, A2.y);
    }

    // self loop: + z[n] (w=1), then everything * dis[n], + bc
    float4 s0 = Z[n * 3], s1 = Z[n * 3 + 1], s2 = Z[n * 3 + 2];
    A0.x += s0.x; A0.y += s0.y; A0.z += s0.z; A0.w += s0.w;
    A1.x += s1.x; A1.y += s1.y; A1.z += s1.z; A1.w += s1.w;
    A2.x += s2.x; A2.y += s2.y;

    float d = dis[n];
    float v[10] = { A0.x, A0.y, A0.z, A0.w, A1.x, A1.y, A1.z, A1.w, A2.x, A2.y };
    float o = sbo;
    #pragma unroll
    for (int k = 0; k < HG; k++)
        o = fmaf(fmaf(v[k], d, sbc[k]), sWo[k], o);
    out[n] = 1.f / (1.f + __expf(-o));
}

// ================= Fallback path (Round-1 scatter) =================
__global__ __launch_bounds__(256) void edge_mlp_kernel(
    const float* __restrict__ x, const float* __restrict__ token,
    const float* __restrict__ eg, const float* __restrict__ ee,
    const float* __restrict__ gum, const int* __restrict__ eidx,
    const float* __restrict__ W0, const float* __restrict__ b0,
    const float* __restrict__ W1, const float* __restrict__ b1,
    const float* __restrict__ W2, const float* __restrict__ b2,
    const float* __restrict__ W3, const float* __restrict__ b3,
    const float* __restrict__ Wl, const float* __restrict__ bl,
    float* __restrict__ ew_out, float* __restrict__ deg)
{
    __shared__ float sW0[13 * HM];
    __shared__ float sW1[HM * HM];
    __shared__ float sW2[HM * HM];
    __shared__ float sW3f[HM * 2];
    __shared__ float sb0[HM], sb1[HM], sb2[HM], sb3[2];
    __shared__ float sWl, sbl;

    for (int i = threadIdx.x; i < 13 * HM; i += 256) sW0[i] = W0[i];
    for (int i = threadIdx.x; i < HM * HM; i += 256) sW1[i] = W1[i];
    for (int i = threadIdx.x; i < HM * HM; i += 256) sW2[i] = W2[i];
    for (int i = threadIdx.x; i < HM * 2; i += 256) sW3f[i] = W3[i];
    if (threadIdx.x < HM) {
        sb0[threadIdx.x] = b0[threadIdx.x];
        sb1[threadIdx.x] = b1[threadIdx.x];
        sb2[threadIdx.x] = b2[threadIdx.x];
    }
    if (threadIdx.x < 2) sb3[threadIdx.x] = b3[threadIdx.x];
    if (threadIdx.x == 0) { sWl = Wl[0]; sbl = bl[0]; }
    __syncthreads();

    int e = blockIdx.x * 256 + threadIdx.x;
    if (e >= NE) return;
    int s = eidx[e];
    int t = eidx[NE + e];

    float ef[13];
    ef[0] = x[s];
    #pragma unroll
    for (int i = 0; i < 5; i++) ef[1 + i] = token[s * 5 + i];
    ef[6] = x[t];
    #pragma unroll
    for (int i = 0; i < 5; i++) ef[7 + i] = token[t * 5 + i];
    ef[12] = eg[e];

    float h[HM], h2[HM];
    #pragma unroll
    for (int j = 0; j < HM; j++) {
        float a = sb0[j];
        #pragma unroll
        for (int i = 0; i < 13; i++) a = fmaf(ef[i], sW0[i * HM + j], a);
        h[j] = a > 0.f ? a : 0.f;
    }
    #pragma unroll
    for (int j = 0; j < HM; j++) {
        float a = sb1[j];
        #pragma unroll
        for (int i = 0; i < HM; i++) a = fmaf(h[i], sW1[i * HM + j], a);
        h2[j] = a > 0.f ? a : 0.f;
    }
    #pragma unroll
    for (int j = 0; j < HM; j++) {
        float a = sb2[j];
        #pragma unroll
        for (int i = 0; i < HM; i++) a = fmaf(h2[i], sW2[i * HM + j], a);
        h[j] = a > 0.f ? a : 0.f;
    }
    float l0 = sb3[0], l1 = sb3[1];
    #pragma unroll
    for (int i = 0; i < HM; i++) {
        l0 = fmaf(h[i], sW3f[i * 2 + 0], l0);
        l1 = fmaf(h[i], sW3f[i * 2 + 1], l1);
    }
    const float2 g2 = ((const float2*)gum)[e];
    float v0 = l0 + g2.x, v1 = l1 + g2.y;
    float ew = 0.f;
    if (!(v1 > v0)) {
        const float2 ee2 = ((const float2*)ee)[e];
        float z = fmaf(ee2.x, sWl, sbl);
        ew = ee2.y / (1.f + __expf(-z));
    }
    ew_out[e] = ew;
    if (ew != 0.f) atomicAdd(&deg[t], ew);
}

__global__ __launch_bounds__(256) void node_pre_kernel(
    const float* __restrict__ x, const float* __restrict__ token,
    const float* __restrict__ Wc, const float* __restrict__ deg,
    float* __restrict__ xw, float* __restrict__ dis)
{
    __shared__ float sWc[6 * HG];
    if (threadIdx.x < 6 * HG) sWc[threadIdx.x] = Wc[threadIdx.x];
    __syncthreads();
    int n = blockIdx.x * 256 + threadIdx.x;
    if (n >= NN) return;
    float xa[6];
    xa[0] = x[n];
    #pragma unroll
    for (int i = 0; i < 5; i++) xa[1 + i] = token[n * 5 + i];
    #pragma unroll
    for (int k = 0; k < HG; k++) {
        float a = 0.f;
        #pragma unroll
        for (int i = 0; i < 6; i++) a = fmaf(xa[i], sWc[i * HG + k], a);
        xw[n * HG + k] = a;
    }
    dis[n] = rsqrtf(deg[n] + 1.0f);
}

__global__ __launch_bounds__(256) void edge_scatter_kernel(
    const int* __restrict__ eidx, const float* __restrict__ ew,
    const float* __restrict__ dis, const float* __restrict__ xw,
    float* __restrict__ agg)
{
    int e = blockIdx.x * 256 + threadIdx.x;
    if (e >= NE) return;
    float w = ew[e];
    if (w == 0.f) return;
    int s = eidx[e];
    int t = eidx[NE + e];
    float norm = dis[s] * w * dis[t];
    #pragma unroll
    for (int k = 0; k < HG; k++)
        atomicAdd(&agg[t * HG + k], norm * xw[s * HG + k]);
}

__global__ __launch_bounds__(256) void node_out_kernel(
    const float* __restrict__ agg, const float* __restrict__ xw,
    const float* __restrict__ dis, const float* __restrict__ bc,
    const float* __restrict__ Wo, const float* __restrict__ bo,
    float* __restrict__ out)
{
    __shared__ float sbc[HG], sWo[HG], sbo;
    if (threadIdx.x < HG) { sbc[threadIdx.x] = bc[threadIdx.x]; sWo[threadIdx.x] = Wo[threadIdx.x]; }
    if (threadIdx.x == 0) sbo = bo[0];
    __syncthreads();
    int n = blockIdx.x * 256 + threadIdx.x;
    if (n >= NN) return;
    float d = dis[n];
    float self = d * d;
    float acc = sbo;
    #pragma unroll
    for (int k = 0; k < HG; k++) {
        float v = agg[n * HG + k] + xw[n * HG + k] * self + sbc[k];
        acc = fmaf(v, sWo[k], acc);
    }
    out[n] = 1.f / (1.f + __expf(-acc));
}

extern "C" void kernel_launch(void* const* d_in, const int* in_sizes, int n_in,
                              void* d_out, int out_size, void* d_ws, size_t ws_size,
                              hipStream_t stream) {
    const float* x   = (const float*)d_in[0];
    const float* tok = (const float*)d_in[1];
    const float* eg  = (const float*)d_in[2];
    const float* ee  = (const float*)d_in[3];
    const float* gum = (const float*)d_in[4];
    const int*   ei  = (const int*)d_in[5];
    const float* W0  = (const float*)d_in[6];
    const float* b0  = (const float*)d_in[7];
    const float* W1  = (const float*)d_in[8];
    const float* b1  = (const float*)d_in[9];
    const float* W2  = (const float*)d_in[10];
    const float* b2  = (const float*)d_in[11];
    const float* W3  = (const float*)d_in[12];
    const float* b3  = (const float*)d_in[13];
    const float* Wl  = (const float*)d_in[14];
    const float* bl  = (const float*)d_in[15];
    const float* Wc  = (const float*)d_in[16];
    const float* bc  = (const float*)d_in[17];
    const float* Wo  = (const float*)d_in[18];
    const float* bo  = (const float*)d_in[19];
    float* out = (float*)d_out;

    dim3 blk(256);
    dim3 egrid(NE / 256);               // exact: 12500
    dim3 ngrid((NN + 255) / 256);

    // New-path ws layout (float offsets)
    size_t off_xall8 = 0;                              // NN*8
    size_t off_xwp   = off_xall8 + (size_t)NN * 8;     // NN*12
    size_t off_slots = off_xwp + (size_t)NN * 12;      // NN*MAXK*2
    size_t off_cnt   = off_slots + (size_t)NN * MAXK * 2; // NN int
    size_t off_novf  = off_cnt + NN;                   // 1 int
    size_t off_dis   = off_novf + 1;                   // NN
    size_t off_ohead = off_dis + NN;                   // NN int
    size_t off_ovfw  = off_ohead + NN;                 // OVF_CAP
    size_t off_ovfs  = off_ovfw + OVF_CAP;             // OVF_CAP int
    size_t off_onxt  = off_ovfs + OVF_CAP;             // OVF_CAP int
    size_t off_w0t   = (off_onxt + OVF_CAP + 15) & ~(size_t)15; // 30*16, 64B-aligned rows
    size_t off_w1t   = off_w0t + 30 * 16;              // 30*32 (offset mult of 32)
    size_t off_w2t   = off_w1t + 30 * 32;              // 30*32
    size_t need_new  = (off_w2t + 30 * 32) * sizeof(float);

    if (ws_size >= need_new) {
        float*  ws    = (float*)d_ws;
        float*  xall8 = ws + off_xall8;
        float*  xwp   = ws + off_xwp;
        float2* slots = (float2*)(ws + off_slots);
        int*    cnt   = (int*)(ws + off_cnt);
        int*    novf  = (int*)(ws + off_novf);
        float*  dis   = ws + off_dis;
        int*    ohead = (int*)(ws + off_ohead);
        float*  ovf_w = ws + off_ovfw;
        int*    ovf_s = (int*)(ws + off_ovfs);
        int*    onxt  = (int*)(ws + off_onxt);
        float*  W0T   = ws + off_w0t;
        float*  W1T   = ws + off_w1t;
        float*  W2T   = ws + off_w2t;

        hipMemsetAsync(cnt, 0, (size_t)(NN + 1) * sizeof(int), stream);   // cnt + novf
        hipMemsetAsync(ohead, 0xFF, (size_t)NN * sizeof(int), stream);    // ohead = -1

        wtrans_kernel<<<dim3(1), blk, 0, stream>>>(W0, W1, W2, W0T, W1T, W2T);
        pack_kernel<<<ngrid, blk, 0, stream>>>(x, tok, Wc, xall8, xwp);
        edge_mlp5_kernel<<<egrid, blk, 0, stream>>>(xall8, eg, ee, gum, ei,
                                                    W0T, b0, W1T, b1, W2T, b2,
                                                    W3, b3, Wl, bl, slots, cnt,
                                                    ohead, onxt, ovf_w, ovf_s, novf);
        node_deg_kernel<<<ngrid, blk, 0, stream>>>(slots, cnt, ohead, onxt, ovf_w,
                                                   xwp, dis);
        gather_out2_kernel<<<ngrid, blk, 0, stream>>>(slots, cnt, ohead, onxt,
                                                      ovf_w, ovf_s, xwp, dis,
                                                      bc, Wo, bo, out);
    } else {
        // Fallback: Round-1 scatter layout: [ew: NE][deg: NN][agg: NN*HG][xw: NN*HG][dis: NN]
        float* ws  = (float*)d_ws;
        float* ew  = ws;
        float* deg = ew + NE;
        float* agg = deg + NN;
        float* xw  = agg + (size_t)NN * HG;
        float* dis = xw + (size_t)NN * HG;

        hipMemsetAsync(deg, 0, (size_t)(NN + (size_t)NN * HG) * sizeof(float), stream);
        edge_mlp_kernel<<<egrid, blk, 0, stream>>>(x, tok, eg, ee, gum, ei,
                                                   W0, b0, W1, b1, W2, b2, W3, b3,
                                                   Wl, bl, ew, deg);
        node_pre_kernel<<<ngrid, blk, 0, stream>>>(x, tok, Wc, deg, xw, dis);
        edge_scatter_kernel<<<egrid, blk, 0, stream>>>(ei, ew, dis, xw, agg);
        node_out_kernel<<<ngrid, blk, 0, stream>>>(agg, xw, dis, bc, Wo, bo, out);
    }
}

// Round 7
// 396.754 us; speedup vs baseline: 2.5909x; 1.0461x over previous
//
#include <hip/hip_runtime.h>

#define NN 100000
#define NE 3200000
#define HM 30
#define HG 10
#define MAXK 26
#define OVF_CAP 8192

typedef float __attribute__((ext_vector_type(2))) f32x2;

__device__ __forceinline__ f32x2 pkfma(f32x2 a, f32x2 b, f32x2 c) {
#if __has_builtin(__builtin_elementwise_fma)
    return __builtin_elementwise_fma(a, b, c);
#else
    f32x2 r; r.x = fmaf(a.x, b.x, c.x); r.y = fmaf(a.y, b.y, c.y); return r;
#endif
}

// ---------------- Stage -1: transpose+pad weights into ws ----------------
// W0T[30][16] (cols 13..15 zeroed), W1T/W2T[30][32] (cols 30..31 zeroed).
// j-outer MLP reads each output's weights as consecutive float2 pairs ->
// scalar (SGPR) loads feeding v_pk_fma_f32.
__global__ __launch_bounds__(256) void wtrans_kernel(
    const float* __restrict__ W0, const float* __restrict__ W1,
    const float* __restrict__ W2,
    float* __restrict__ W0T, float* __restrict__ W1T, float* __restrict__ W2T)
{
    for (int idx = threadIdx.x; idx < HM * 16; idx += 256) {
        int j = idx >> 4, i = idx & 15;
        W0T[idx] = (i < 13) ? W0[i * HM + j] : 0.f;
    }
    for (int idx = threadIdx.x; idx < HM * 32; idx += 256) {
        int j = idx >> 5, i = idx & 31;
        float v1 = (i < HM) ? W1[i * HM + j] : 0.f;
        float v2 = (i < HM) ? W2[i * HM + j] : 0.f;
        W1T[idx] = v1;
        W2T[idx] = v2;
    }
}

// ---------------- Stage 0: pack node features + xw ----------------
__global__ __launch_bounds__(256) void pack_kernel(
    const float* __restrict__ x, const float* __restrict__ token,
    const float* __restrict__ Wc,
    float* __restrict__ xall8, float* __restrict__ xwp)
{
    __shared__ float sWc[6 * HG];
    if (threadIdx.x < 6 * HG) sWc[threadIdx.x] = Wc[threadIdx.x];
    __syncthreads();

    int n = blockIdx.x * 256 + threadIdx.x;
    if (n >= NN) return;

    float xa[6];
    xa[0] = x[n];
    #pragma unroll
    for (int i = 0; i < 5; i++) xa[1 + i] = token[n * 5 + i];

    float4* x4 = (float4*)xall8;
    x4[n * 2 + 0] = make_float4(xa[0], xa[1], xa[2], xa[3]);
    x4[n * 2 + 1] = make_float4(xa[4], xa[5], 0.f, 0.f);

    float w[12];
    #pragma unroll
    for (int k = 0; k < HG; k++) {
        float a = 0.f;
        #pragma unroll
        for (int i = 0; i < 6; i++) a = fmaf(xa[i], sWc[i * HG + k], a);
        w[k] = a;
    }
    w[10] = 0.f; w[11] = 0.f;
    float4* wp = (float4*)(xwp + (size_t)n * 12);
    wp[0] = make_float4(w[0], w[1], w[2], w[3]);
    wp[1] = make_float4(w[4], w[5], w[6], w[7]);
    wp[2] = make_float4(w[8], w[9], w[10], w[11]);
}

// ---------------- Stage 1: per-edge MLP ----------------
// __launch_bounds__(256, 2): min 2 waves/EU -> VGPR budget ~256, so the
// ~100 live floats (h[30]+g[30]+ef+temps) stay in ARCH VGPRs. Rounds 0/3/5
// all reported VGPR 36-48 with >80 live values: the allocator was parking
// state in AGPRs and every access was a v_accvgpr move -> the constant
// ~210us VALU time (2.1x the FMA floor) across all prior variants.
// v_pk_fma_f32 (bit-exact fp32) via float2 halves FMA instruction count;
// weight pairs are contiguous in the transposed rows -> scalar loads.
__global__ __launch_bounds__(256, 2) void edge_mlp6_kernel(
    const float* __restrict__ xall8,
    const float* __restrict__ eg, const float* __restrict__ ee,
    const float* __restrict__ gum, const int* __restrict__ eidx,
    const float* __restrict__ W0T, const float* __restrict__ b0,
    const float* __restrict__ W1T, const float* __restrict__ b1,
    const float* __restrict__ W2T, const float* __restrict__ b2,
    const float* __restrict__ W3, const float* __restrict__ b3,
    const float* __restrict__ Wl, const float* __restrict__ bl,
    float2* __restrict__ slots, int* __restrict__ cnt, float* __restrict__ deg,
    int* __restrict__ ohead, int* __restrict__ onxt,
    float* __restrict__ ovf_w, int* __restrict__ ovf_s, int* __restrict__ novf)
{
    int e = blockIdx.x * 256 + threadIdx.x;   // NE == 12500*256 exactly
    int s = eidx[e];
    int t = eidx[NE + e];

    const float4* x4 = (const float4*)xall8;
    float4 qa = x4[s * 2], qb = x4[s * 2 + 1];
    float4 qc = x4[t * 2], qd = x4[t * 2 + 1];

    f32x2 ef2[7];
    ef2[0] = f32x2{ qa.x, qa.y };
    ef2[1] = f32x2{ qa.z, qa.w };
    ef2[2] = f32x2{ qb.x, qb.y };
    ef2[3] = f32x2{ qc.x, qc.y };
    ef2[4] = f32x2{ qc.z, qc.w };
    ef2[5] = f32x2{ qd.x, qd.y };
    ef2[6] = f32x2{ eg[e], 0.f };

    float h[HM], g[HM];

    #pragma unroll
    for (int j = 0; j < HM; j++) {
        const f32x2* w2 = (const f32x2*)(W0T + j * 16);
        f32x2 a2 = f32x2{ b0[j], 0.f };
        #pragma unroll
        for (int p = 0; p < 7; p++) a2 = pkfma(ef2[p], w2[p], a2);
        h[j] = fmaxf(a2.x + a2.y, 0.f);
    }

    {
        f32x2 hp[15];
        #pragma unroll
        for (int p = 0; p < 15; p++) hp[p] = f32x2{ h[2 * p], h[2 * p + 1] };
        #pragma unroll
        for (int j = 0; j < HM; j++) {
            const f32x2* w2 = (const f32x2*)(W1T + j * 32);
            f32x2 a2 = f32x2{ b1[j], 0.f };
            #pragma unroll
            for (int p = 0; p < 15; p++) a2 = pkfma(hp[p], w2[p], a2);
            g[j] = fmaxf(a2.x + a2.y, 0.f);
        }
    }
    {
        f32x2 gp[15];
        #pragma unroll
        for (int p = 0; p < 15; p++) gp[p] = f32x2{ g[2 * p], g[2 * p + 1] };
        #pragma unroll
        for (int j = 0; j < HM; j++) {
            const f32x2* w2 = (const f32x2*)(W2T + j * 32);
            f32x2 a2 = f32x2{ b2[j], 0.f };
            #pragma unroll
            for (int p = 0; p < 15; p++) a2 = pkfma(gp[p], w2[p], a2);
            h[j] = fmaxf(a2.x + a2.y, 0.f);
        }
    }

    float l0 = b3[0], l1 = b3[1];
    #pragma unroll
    for (int i = 0; i < HM; i++) {
        l0 = fmaf(h[i], W3[i * 2 + 0], l0);
        l1 = fmaf(h[i], W3[i * 2 + 1], l1);
    }

    const float2 g2 = ((const float2*)gum)[e];
    float v0 = l0 + g2.x;
    float v1 = l1 + g2.y;

    // forward: edge_value = (v1 > v0) ? 1 : 0; active iff edge_value == 0
    float ew = 0.f;
    if (!(v1 > v0)) {
        const float2 e2 = ((const float2*)ee)[e];
        float z = fmaf(e2.x, Wl[0], bl[0]);
        ew = e2.y / (1.f + __expf(-z));
    }
    if (ew != 0.f) {
        atomicAdd(&deg[t], ew);          // deg accumulated here: node pass
                                         // no longer re-reads slots
        int slot = atomicAdd(&cnt[t], 1);
        if (slot < MAXK) {
            slots[(size_t)t * MAXK + slot] = make_float2(ew, __int_as_float(s));
        } else {
            int i = atomicAdd(novf, 1);
            if (i < OVF_CAP) {
                ovf_w[i] = ew;
                ovf_s[i] = s;
                onxt[i] = atomicExch(&ohead[t], i);
            }
        }
    }
}

// ---------------- Stage 2: trivial per-node dis ----------------
__global__ __launch_bounds__(256) void node_dis_kernel(
    const float* __restrict__ deg, float* __restrict__ dis)
{
    int n = blockIdx.x * 256 + threadIdx.x;
    if (n >= NN) return;
    dis[n] = rsqrtf(deg[n] + 1.0f);   // +1 = self loop
}

// ---------------- Stage 3: gather, 4 lanes per node ----------------
// Old version: 391 blocks -> ~1.5 waves/SIMD, dependent slot->z loads fully
// latency-exposed. 4 lanes/node quadruples resident waves; partial sums
// reduced with 2 rounds of shfl_xor within each aligned 4-lane group.
__global__ __launch_bounds__(256) void gather_out3_kernel(
    const float2* __restrict__ slots, const int* __restrict__ cnt,
    const int* __restrict__ ohead, const int* __restrict__ onxt,
    const float* __restrict__ ovf_w, const int* __restrict__ ovf_s,
    const float* __restrict__ xwp, const float* __restrict__ dis,
    const float* __restrict__ bc, const float* __restrict__ Wo,
    const float* __restrict__ bo, float* __restrict__ out)
{
    __shared__ float sbc[12], sWo[12], sbo;
    if (threadIdx.x < 12) {
        sbc[threadIdx.x] = (threadIdx.x < HG) ? bc[threadIdx.x] : 0.f;
        sWo[threadIdx.x] = (threadIdx.x < HG) ? Wo[threadIdx.x] : 0.f;
    }
    if (threadIdx.x == 0) sbo = bo[0];
    __syncthreads();

    int tg = blockIdx.x * 256 + threadIdx.x;
    int n = tg >> 2;
    int k = tg & 3;
    if (n >= NN) return;

    const float4* Z = (const float4*)xwp;
    float4 A0 = make_float4(0.f, 0.f, 0.f, 0.f), A1 = A0, A2 = A0;

    int c = cnt[n];
    int cc = c < MAXK ? c : MAXK;
    for (int j = k; j < cc; j += 4) {
        float2 p = slots[(size_t)n * MAXK + j];
        int s = __float_as_int(p.y);
        float w = p.x * dis[s];
        float4 z0 = Z[s * 3], z1 = Z[s * 3 + 1], z2 = Z[s * 3 + 2];
        A0.x = fmaf(w, z0.x, A0.x); A0.y = fmaf(w, z0.y, A0.y);
        A0.z = fmaf(w, z0.z, A0.z); A0.w = fmaf(w, z0.w, A0.w);
        A1.x = fmaf(w, z1.x, A1.x); A1.y = fmaf(w, z1.y, A1.y);
        A1.z = fmaf(w, z1.z, A1.z); A1.w = fmaf(w, z1.w, A1.w);
        A2.x = fmaf(w, z2.x, A2.x); A2.y = fmaf(w, z2.y, A2.y);
    }
    if (k == 0) {
        for (int i = ohead[n]; i >= 0; i = onxt[i]) {
            int s = ovf_s[i];
            float w = ovf_w[i] * dis[s];
            float4 z0 = Z[s * 3], z1 = Z[s * 3 + 1], z2 = Z[s * 3 + 2];
            A0.x = fmaf(w, z0.x, A0.x); A0.y = fmaf(w, z0.y, A0.y);
            A0.z = fmaf(w, z0.z, A0.z); A0.w = fmaf(w, z0.w, A0.w);
            A1.x = fmaf(w, z1.x, A1.x); A1.y = fmaf(w, z1.y, A1.y);
            A1.z = fmaf(w, z1.z, A1.z); A1.w = fmaf(w, z1.w, A1.w);
            A2.x = fmaf(w, z2.x, A2.x); A2.y = fmaf(w, z2.y, A2.y);
        }
        // self loop: w = 1 * dis[n]
        float wn = dis[n];
        float4 s0 = Z[n * 3], s1 = Z[n * 3 + 1], s2 = Z[n * 3 + 2];
        A0.x = fmaf(wn, s0.x, A0.x); A0.y = fmaf(wn, s0.y, A0.y);
        A0.z = fmaf(wn, s0.z, A0.z); A0.w = fmaf(wn, s0.w, A0.w);
        A1.x = fmaf(wn, s1.x, A1.x); A1.y = fmaf(wn, s1.y, A1.y);
        A1.z = fmaf(wn, s1.z, A1.z); A1.w = fmaf(wn, s1.w, A1.w);
        A2.x = fmaf(wn, s2.x, A2.x); A2.y = fmaf(wn, s2.y, A2.y);
    }

    float v[10] = { A0.x, A0.y, A0.z, A0.w, A1.x, A1.y, A1.z, A1.w, A2.x, A2.y };
    #pragma unroll
    for (int q = 0; q < 10; q++) {
        v[q] += __shfl_xor(v[q], 1);
        v[q] += __shfl_xor(v[q], 2);
    }

    if (k == 0) {
        float d = dis[n];
        float o = sbo;
        #pragma unroll
        for (int q = 0; q < HG; q++)
            o = fmaf(fmaf(v[q], d, sbc[q]), sWo[q], o);
        out[n] = 1.f / (1.f + __expf(-o));
    }
}

// ================= Fallback path (Round-1 scatter) =================
__global__ __launch_bounds__(256) void edge_mlp_kernel(
    const float* __restrict__ x, const float* __restrict__ token,
    const float* __restrict__ eg, const float* __restrict__ ee,
    const float* __restrict__ gum, const int* __restrict__ eidx,
    const float* __restrict__ W0, const float* __restrict__ b0,
    const float* __restrict__ W1, const float* __restrict__ b1,
    const float* __restrict__ W2, const float* __restrict__ b2,
    const float* __restrict__ W3, const float* __restrict__ b3,
    const float* __restrict__ Wl, const float* __restrict__ bl,
    float* __restrict__ ew_out, float* __restrict__ deg)
{
    __shared__ float sW0[13 * HM];
    __shared__ float sW1[HM * HM];
    __shared__ float sW2[HM * HM];
    __shared__ float sW3f[HM * 2];
    __shared__ float sb0[HM], sb1[HM], sb2[HM], sb3[2];
    __shared__ float sWl, sbl;

    for (int i = threadIdx.x; i < 13 * HM; i += 256) sW0[i] = W0[i];
    for (int i = threadIdx.x; i < HM * HM; i += 256) sW1[i] = W1[i];
    for (int i = threadIdx.x; i < HM * HM; i += 256) sW2[i] = W2[i];
    for (int i = threadIdx.x; i < HM * 2; i += 256) sW3f[i] = W3[i];
    if (threadIdx.x < HM) {
        sb0[threadIdx.x] = b0[threadIdx.x];
        sb1[threadIdx.x] = b1[threadIdx.x];
        sb2[threadIdx.x] = b2[threadIdx.x];
    }
    if (threadIdx.x < 2) sb3[threadIdx.x] = b3[threadIdx.x];
    if (threadIdx.x == 0) { sWl = Wl[0]; sbl = bl[0]; }
    __syncthreads();

    int e = blockIdx.x * 256 + threadIdx.x;
    if (e >= NE) return;
    int s = eidx[e];
    int t = eidx[NE + e];

    float ef[13];
    ef[0] = x[s];
    #pragma unroll
    for (int i = 0; i < 5; i++) ef[1 + i] = token[s * 5 + i];
    ef[6] = x[t];
    #pragma unroll
    for (int i = 0; i < 5; i++) ef[7 + i] = token[t * 5 + i];
    ef[12] = eg[e];

    float h[HM], h2[HM];
    #pragma unroll
    for (int j = 0; j < HM; j++) {
        float a = sb0[j];
        #pragma unroll
        for (int i = 0; i < 13; i++) a = fmaf(ef[i], sW0[i * HM + j], a);
        h[j] = a > 0.f ? a : 0.f;
    }
    #pragma unroll
    for (int j = 0; j < HM; j++) {
        float a = sb1[j];
        #pragma unroll
        for (int i = 0; i < HM; i++) a = fmaf(h[i], sW1[i * HM + j], a);
        h2[j] = a > 0.f ? a : 0.f;
    }
    #pragma unroll
    for (int j = 0; j < HM; j++) {
        float a = sb2[j];
        #pragma unroll
        for (int i = 0; i < HM; i++) a = fmaf(h2[i], sW2[i * HM + j], a);
        h[j] = a > 0.f ? a : 0.f;
    }
    float l0 = sb3[0], l1 = sb3[1];
    #pragma unroll
    for (int i = 0; i < HM; i++) {
        l0 = fmaf(h[i], sW3f[i * 2 + 0], l0);
        l1 = fmaf(h[i], sW3f[i * 2 + 1], l1);
    }
    const float2 g2 = ((const float2*)gum)[e];
    float v0 = l0 + g2.x, v1 = l1 + g2.y;
    float ew = 0.f;
    if (!(v1 > v0)) {
        const float2 ee2 = ((const float2*)ee)[e];
        float z = fmaf(ee2.x, sWl, sbl);
        ew = ee2.y / (1.f + __expf(-z));
    }
    ew_out[e] = ew;
    if (ew != 0.f) atomicAdd(&deg[t], ew);
}

__global__ __launch_bounds__(256) void node_pre_kernel(
    const float* __restrict__ x, const float* __restrict__ token,
    const float* __restrict__ Wc, const float* __restrict__ deg,
    float* __restrict__ xw, float* __restrict__ dis)
{
    __shared__ float sWc[6 * HG];
    if (threadIdx.x < 6 * HG) sWc[threadIdx.x] = Wc[threadIdx.x];
    __syncthreads();
    int n = blockIdx.x * 256 + threadIdx.x;
    if (n >= NN) return;
    float xa[6];
    xa[0] = x[n];
    #pragma unroll
    for (int i = 0; i < 5; i++) xa[1 + i] = token[n * 5 + i];
    #pragma unroll
    for (int k = 0; k < HG; k++) {
        float a = 0.f;
        #pragma unroll
        for (int i = 0; i < 6; i++) a = fmaf(xa[i], sWc[i * HG + k], a);
        xw[n * HG + k] = a;
    }
    dis[n] = rsqrtf(deg[n] + 1.0f);
}

__global__ __launch_bounds__(256) void edge_scatter_kernel(
    const int* __restrict__ eidx, const float* __restrict__ ew,
    const float* __restrict__ dis, const float* __restrict__ xw,
    float* __restrict__ agg)
{
    int e = blockIdx.x * 256 + threadIdx.x;
    if (e >= NE) return;
    float w = ew[e];
    if (w == 0.f) return;
    int s = eidx[e];
    int t = eidx[NE + e];
    float norm = dis[s] * w * dis[t];
    #pragma unroll
    for (int k = 0; k < HG; k++)
        atomicAdd(&agg[t * HG + k], norm * xw[s * HG + k]);
}

__global__ __launch_bounds__(256) void node_out_kernel(
    const float* __restrict__ agg, const float* __restrict__ xw,
    const float* __restrict__ dis, const float* __restrict__ bc,
    const float* __restrict__ Wo, const float* __restrict__ bo,
    float* __restrict__ out)
{
    __shared__ float sbc[HG], sWo[HG], sbo;
    if (threadIdx.x < HG) { sbc[threadIdx.x] = bc[threadIdx.x]; sWo[threadIdx.x] = Wo[threadIdx.x]; }
    if (threadIdx.x == 0) sbo = bo[0];
    __syncthreads();
    int n = blockIdx.x * 256 + threadIdx.x;
    if (n >= NN) return;
    float d = dis[n];
    float self = d * d;
    float acc = sbo;
    #pragma unroll
    for (int k = 0; k < HG; k++) {
        float v = agg[n * HG + k] + xw[n * HG + k] * self + sbc[k];
        acc = fmaf(v, sWo[k], acc);
    }
    out[n] = 1.f / (1.f + __expf(-acc));
}

extern "C" void kernel_launch(void* const* d_in, const int* in_sizes, int n_in,
                              void* d_out, int out_size, void* d_ws, size_t ws_size,
                              hipStream_t stream) {
    const float* x   = (const float*)d_in[0];
    const float* tok = (const float*)d_in[1];
    const float* eg  = (const float*)d_in[2];
    const float* ee  = (const float*)d_in[3];
    const float* gum = (const float*)d_in[4];
    const int*   ei  = (const int*)d_in[5];
    const float* W0  = (const float*)d_in[6];
    const float* b0  = (const float*)d_in[7];
    const float* W1  = (const float*)d_in[8];
    const float* b1  = (const float*)d_in[9];
    const float* W2  = (const float*)d_in[10];
    const float* b2  = (const float*)d_in[11];
    const float* W3  = (const float*)d_in[12];
    const float* b3  = (const float*)d_in[13];
    const float* Wl  = (const float*)d_in[14];
    const float* bl  = (const float*)d_in[15];
    const float* Wc  = (const float*)d_in[16];
    const float* bc  = (const float*)d_in[17];
    const float* Wo  = (const float*)d_in[18];
    const float* bo  = (const float*)d_in[19];
    float* out = (float*)d_out;

    dim3 blk(256);
    dim3 egrid(NE / 256);               // exact: 12500
    dim3 ngrid((NN + 255) / 256);
    dim3 g4grid((NN * 4 + 255) / 256);  // 4 lanes per node

    // New-path ws layout (float offsets)
    size_t off_xall8 = 0;                              // NN*8
    size_t off_xwp   = off_xall8 + (size_t)NN * 8;     // NN*12
    size_t off_slots = off_xwp + (size_t)NN * 12;      // NN*MAXK*2
    size_t off_cnt   = off_slots + (size_t)NN * MAXK * 2; // NN int
    size_t off_novf  = off_cnt + NN;                   // 1 int
    size_t off_deg   = off_novf + 1;                   // NN float (zeroed with cnt)
    size_t off_dis   = off_deg + NN;                   // NN
    size_t off_ohead = off_dis + NN;                   // NN int
    size_t off_ovfw  = off_ohead + NN;                 // OVF_CAP
    size_t off_ovfs  = off_ovfw + OVF_CAP;             // OVF_CAP int
    size_t off_onxt  = off_ovfs + OVF_CAP;             // OVF_CAP int
    size_t off_w0t   = (off_onxt + OVF_CAP + 15) & ~(size_t)15; // 30*16
    size_t off_w1t   = off_w0t + 30 * 16;              // 30*32
    size_t off_w2t   = off_w1t + 30 * 32;              // 30*32
    size_t need_new  = (off_w2t + 30 * 32) * sizeof(float);

    if (ws_size >= need_new) {
        float*  ws    = (float*)d_ws;
        float*  xall8 = ws + off_xall8;
        float*  xwp   = ws + off_xwp;
        float2* slots = (float2*)(ws + off_slots);
        int*    cnt   = (int*)(ws + off_cnt);
        int*    novf  = (int*)(ws + off_novf);
        float*  deg   = ws + off_deg;
        float*  dis   = ws + off_dis;
        int*    ohead = (int*)(ws + off_ohead);
        float*  ovf_w = ws + off_ovfw;
        int*    ovf_s = (int*)(ws + off_ovfs);
        int*    onxt  = (int*)(ws + off_onxt);
        float*  W0T   = ws + off_w0t;
        float*  W1T   = ws + off_w1t;
        float*  W2T   = ws + off_w2t;

        // cnt(NN) + novf(1) + deg(NN) are contiguous: one zeroing memset
        hipMemsetAsync(cnt, 0, (size_t)(2 * NN + 1) * sizeof(int), stream);
        hipMemsetAsync(ohead, 0xFF, (size_t)NN * sizeof(int), stream);    // ohead = -1

        wtrans_kernel<<<dim3(1), blk, 0, stream>>>(W0, W1, W2, W0T, W1T, W2T);
        pack_kernel<<<ngrid, blk, 0, stream>>>(x, tok, Wc, xall8, xwp);
        edge_mlp6_kernel<<<egrid, blk, 0, stream>>>(xall8, eg, ee, gum, ei,
                                                    W0T, b0, W1T, b1, W2T, b2,
                                                    W3, b3, Wl, bl, slots, cnt, deg,
                                                    ohead, onxt, ovf_w, ovf_s, novf);
        node_dis_kernel<<<ngrid, blk, 0, stream>>>(deg, dis);
        gather_out3_kernel<<<g4grid, blk, 0, stream>>>(slots, cnt, ohead, onxt,
                                                       ovf_w, ovf_s, xwp, dis,
                                                       bc, Wo, bo, out);
    } else {
        // Fallback: Round-1 scatter layout: [ew: NE][deg: NN][agg: NN*HG][xw: NN*HG][dis: NN]
        float* ws  = (float*)d_ws;
        float* ew  = ws;
        float* deg = ew + NE;
        float* agg = deg + NN;
        float* xw  = agg + (size_t)NN * HG;
        float* dis = xw + (size_t)NN * HG;

        hipMemsetAsync(deg, 0, (size_t)(NN + (size_t)NN * HG) * sizeof(float), stream);
        edge_mlp_kernel<<<egrid, blk, 0, stream>>>(x, tok, eg, ee, gum, ei,
                                                   W0, b0, W1, b1, W2, b2, W3, b3,
                                                   Wl, bl, ew, deg);
        node_pre_kernel<<<ngrid, blk, 0, stream>>>(x, tok, Wc, deg, xw, dis);
        edge_scatter_kernel<<<egrid, blk, 0, stream>>>(ei, ew, dis, xw, agg);
        node_out_kernel<<<ngrid, blk, 0, stream>>>(agg, xw, dis, bc, Wo, bo, out);
    }
}

// Round 8
// 375.737 us; speedup vs baseline: 2.7358x; 1.0559x over previous
//
#include <hip/hip_runtime.h>

#define NN 100000
#define NE 3200000
#define HM 30
#define HG 10
#define MAXK 26
#define OVF_CAP 8192

typedef float __attribute__((ext_vector_type(2))) f32x2;

__device__ __forceinline__ f32x2 pkfma(f32x2 a, f32x2 b, f32x2 c) {
#if __has_builtin(__builtin_elementwise_fma)
    return __builtin_elementwise_fma(a, b, c);
#else
    f32x2 r; r.x = fmaf(a.x, b.x, c.x); r.y = fmaf(a.y, b.y, c.y); return r;
#endif
}

// ---------------- Stage -1: transpose+pad weights into ws ----------------
__global__ __launch_bounds__(256) void wtrans_kernel(
    const float* __restrict__ W0, const float* __restrict__ W1,
    const float* __restrict__ W2,
    float* __restrict__ W0T, float* __restrict__ W1T, float* __restrict__ W2T)
{
    for (int idx = threadIdx.x; idx < HM * 16; idx += 256) {
        int j = idx >> 4, i = idx & 15;
        W0T[idx] = (i < 13) ? W0[i * HM + j] : 0.f;
    }
    for (int idx = threadIdx.x; idx < HM * 32; idx += 256) {
        int j = idx >> 5, i = idx & 31;
        float v1 = (i < HM) ? W1[i * HM + j] : 0.f;
        float v2 = (i < HM) ? W2[i * HM + j] : 0.f;
        W1T[idx] = v1;
        W2T[idx] = v2;
    }
}

// ---------------- Stage 0: pack node features + xw ----------------
__global__ __launch_bounds__(256) void pack_kernel(
    const float* __restrict__ x, const float* __restrict__ token,
    const float* __restrict__ Wc,
    float* __restrict__ xall8, float* __restrict__ xwp)
{
    __shared__ float sWc[6 * HG];
    if (threadIdx.x < 6 * HG) sWc[threadIdx.x] = Wc[threadIdx.x];
    __syncthreads();

    int n = blockIdx.x * 256 + threadIdx.x;
    if (n >= NN) return;

    float xa[6];
    xa[0] = x[n];
    #pragma unroll
    for (int i = 0; i < 5; i++) xa[1 + i] = token[n * 5 + i];

    float4* x4 = (float4*)xall8;
    x4[n * 2 + 0] = make_float4(xa[0], xa[1], xa[2], xa[3]);
    x4[n * 2 + 1] = make_float4(xa[4], xa[5], 0.f, 0.f);

    float w[12];
    #pragma unroll
    for (int k = 0; k < HG; k++) {
        float a = 0.f;
        #pragma unroll
        for (int i = 0; i < 6; i++) a = fmaf(xa[i], sWc[i * HG + k], a);
        w[k] = a;
    }
    w[10] = 0.f; w[11] = 0.f;
    float4* wp = (float4*)(xwp + (size_t)n * 12);
    wp[0] = make_float4(w[0], w[1], w[2], w[3]);
    wp[1] = make_float4(w[4], w[5], w[6], w[7]);
    wp[2] = make_float4(w[8], w[9], w[10], w[11]);
}

// ---------------- Stage 1: per-edge MLP (pk scalar weights, NO deg atomic) --
// Round-7 counters: deg atomicAdd added ~116MB of cross-XCD atomic line
// traffic (FETCH +66MB, WRITE +50MB) and ate the pk-FMA gain. Removed;
// deg is recomputed from slots in node_deg (2.6MB of reads).
__global__ __launch_bounds__(256, 2) void edge_mlp7_kernel(
    const float* __restrict__ xall8,
    const float* __restrict__ eg, const float* __restrict__ ee,
    const float* __restrict__ gum, const int* __restrict__ eidx,
    const float* __restrict__ W0T, const float* __restrict__ b0,
    const float* __restrict__ W1T, const float* __restrict__ b1,
    const float* __restrict__ W2T, const float* __restrict__ b2,
    const float* __restrict__ W3, const float* __restrict__ b3,
    const float* __restrict__ Wl, const float* __restrict__ bl,
    float2* __restrict__ slots, int* __restrict__ cnt,
    int* __restrict__ ohead, int* __restrict__ onxt,
    float* __restrict__ ovf_w, int* __restrict__ ovf_s, int* __restrict__ novf)
{
    int e = blockIdx.x * 256 + threadIdx.x;   // NE == 12500*256 exactly
    int s = eidx[e];
    int t = eidx[NE + e];

    const float4* x4 = (const float4*)xall8;
    float4 qa = x4[s * 2], qb = x4[s * 2 + 1];
    float4 qc = x4[t * 2], qd = x4[t * 2 + 1];

    f32x2 ef2[7];
    ef2[0] = f32x2{ qa.x, qa.y };
    ef2[1] = f32x2{ qa.z, qa.w };
    ef2[2] = f32x2{ qb.x, qb.y };
    ef2[3] = f32x2{ qc.x, qc.y };
    ef2[4] = f32x2{ qc.z, qc.w };
    ef2[5] = f32x2{ qd.x, qd.y };
    ef2[6] = f32x2{ eg[e], 0.f };

    float h[HM], g[HM];

    #pragma unroll
    for (int j = 0; j < HM; j++) {
        const f32x2* w2 = (const f32x2*)(W0T + j * 16);
        f32x2 a2 = f32x2{ b0[j], 0.f };
        #pragma unroll
        for (int p = 0; p < 7; p++) a2 = pkfma(ef2[p], w2[p], a2);
        h[j] = fmaxf(a2.x + a2.y, 0.f);
    }

    {
        f32x2 hp[15];
        #pragma unroll
        for (int p = 0; p < 15; p++) hp[p] = f32x2{ h[2 * p], h[2 * p + 1] };
        #pragma unroll
        for (int j = 0; j < HM; j++) {
            const f32x2* w2 = (const f32x2*)(W1T + j * 32);
            f32x2 a2 = f32x2{ b1[j], 0.f };
            #pragma unroll
            for (int p = 0; p < 15; p++) a2 = pkfma(hp[p], w2[p], a2);
            g[j] = fmaxf(a2.x + a2.y, 0.f);
        }
    }
    {
        f32x2 gp[15];
        #pragma unroll
        for (int p = 0; p < 15; p++) gp[p] = f32x2{ g[2 * p], g[2 * p + 1] };
        #pragma unroll
        for (int j = 0; j < HM; j++) {
            const f32x2* w2 = (const f32x2*)(W2T + j * 32);
            f32x2 a2 = f32x2{ b2[j], 0.f };
            #pragma unroll
            for (int p = 0; p < 15; p++) a2 = pkfma(gp[p], w2[p], a2);
            h[j] = fmaxf(a2.x + a2.y, 0.f);
        }
    }

    float l0 = b3[0], l1 = b3[1];
    #pragma unroll
    for (int i = 0; i < HM; i++) {
        l0 = fmaf(h[i], W3[i * 2 + 0], l0);
        l1 = fmaf(h[i], W3[i * 2 + 1], l1);
    }

    const float2 g2 = ((const float2*)gum)[e];
    float v0 = l0 + g2.x;
    float v1 = l1 + g2.y;

    // forward: edge_value = (v1 > v0) ? 1 : 0; active iff edge_value == 0
    float ew = 0.f;
    if (!(v1 > v0)) {
        const float2 e2 = ((const float2*)ee)[e];
        float z = fmaf(e2.x, Wl[0], bl[0]);
        ew = e2.y / (1.f + __expf(-z));
    }
    if (ew != 0.f) {
        int slot = atomicAdd(&cnt[t], 1);
        if (slot < MAXK) {
            slots[(size_t)t * MAXK + slot] = make_float2(ew, __int_as_float(s));
        } else {
            int i = atomicAdd(novf, 1);
            if (i < OVF_CAP) {
                ovf_w[i] = ew;
                ovf_s[i] = s;
                onxt[i] = atomicExch(&ohead[t], i);
            }
        }
    }
}

// ---------------- Stage 2: per-node deg -> dis; scale xwp in place to z ----
__global__ __launch_bounds__(256) void node_deg_kernel(
    const float2* __restrict__ slots, const int* __restrict__ cnt,
    const int* __restrict__ ohead, const int* __restrict__ onxt,
    const float* __restrict__ ovf_w,
    float* __restrict__ xwp, float* __restrict__ dis)
{
    int n = blockIdx.x * 256 + threadIdx.x;
    if (n >= NN) return;

    int c = cnt[n];
    int cc = c < MAXK ? c : MAXK;
    float deg = 0.f;
    for (int j = 0; j < cc; j++) deg += slots[(size_t)n * MAXK + j].x;
    for (int i = ohead[n]; i >= 0; i = onxt[i]) deg += ovf_w[i];

    float d = rsqrtf(deg + 1.0f);   // +1 = self loop
    dis[n] = d;

    float4* wp = (float4*)(xwp + (size_t)n * 12);
    #pragma unroll
    for (int q = 0; q < 3; q++) {
        float4 v = wp[q];
        v.x *= d; v.y *= d; v.z *= d; v.w *= d;
        wp[q] = v;
    }
}

// ---------------- Stage 3: gather, 4 lanes per node, pre-scaled z ----------
// z = dis[s]*xw[s] is pre-scaled in node_deg -> no dependent dis[s] load in
// the inner loop (round-7 version had one; that ate the 4-lane gain).
__global__ __launch_bounds__(256) void gather_out4_kernel(
    const float2* __restrict__ slots, const int* __restrict__ cnt,
    const int* __restrict__ ohead, const int* __restrict__ onxt,
    const float* __restrict__ ovf_w, const int* __restrict__ ovf_s,
    const float* __restrict__ z, const float* __restrict__ dis,
    const float* __restrict__ bc, const float* __restrict__ Wo,
    const float* __restrict__ bo, float* __restrict__ out)
{
    __shared__ float sbc[12], sWo[12], sbo;
    if (threadIdx.x < 12) {
        sbc[threadIdx.x] = (threadIdx.x < HG) ? bc[threadIdx.x] : 0.f;
        sWo[threadIdx.x] = (threadIdx.x < HG) ? Wo[threadIdx.x] : 0.f;
    }
    if (threadIdx.x == 0) sbo = bo[0];
    __syncthreads();

    int tg = blockIdx.x * 256 + threadIdx.x;
    int n = tg >> 2;
    int k = tg & 3;
    if (n >= NN) return;

    const float4* Z = (const float4*)z;
    float4 A0 = make_float4(0.f, 0.f, 0.f, 0.f), A1 = A0, A2 = A0;

    int c = cnt[n];
    int cc = c < MAXK ? c : MAXK;
    for (int j = k; j < cc; j += 4) {
        float2 p = slots[(size_t)n * MAXK + j];
        float w = p.x;
        int s = __float_as_int(p.y);
        float4 z0 = Z[s * 3], z1 = Z[s * 3 + 1], z2 = Z[s * 3 + 2];
        A0.x = fmaf(w, z0.x, A0.x); A0.y = fmaf(w, z0.y, A0.y);
        A0.z = fmaf(w, z0.z, A0.z); A0.w = fmaf(w, z0.w, A0.w);
        A1.x = fmaf(w, z1.x, A1.x); A1.y = fmaf(w, z1.y, A1.y);
        A1.z = fmaf(w, z1.z, A1.z); A1.w = fmaf(w, z1.w, A1.w);
        A2.x = fmaf(w, z2.x, A2.x); A2.y = fmaf(w, z2.y, A2.y);
    }
    if (k == 0) {
        for (int i = ohead[n]; i >= 0; i = onxt[i]) {
            float w = ovf_w[i];
            int s = ovf_s[i];
            float4 z0 = Z[s * 3], z1 = Z[s * 3 + 1], z2 = Z[s * 3 + 2];
            A0.x = fmaf(w, z0.x, A0.x); A0.y = fmaf(w, z0.y, A0.y);
            A0.z = fmaf(w, z0.z, A0.z); A0.w = fmaf(w, z0.w, A0.w);
            A1.x = fmaf(w, z1.x, A1.x); A1.y = fmaf(w, z1.y, A1.y);
            A1.z = fmaf(w, z1.z, A1.z); A1.w = fmaf(w, z1.w, A1.w);
            A2.x = fmaf(w, z2.x, A2.x); A2.y = fmaf(w, z2.y, A2.y);
        }
        // self loop: + z[n] (w=1)
        float4 s0 = Z[n * 3], s1 = Z[n * 3 + 1], s2 = Z[n * 3 + 2];
        A0.x += s0.x; A0.y += s0.y; A0.z += s0.z; A0.w += s0.w;
        A1.x += s1.x; A1.y += s1.y; A1.z += s1.z; A1.w += s1.w;
        A2.x += s2.x; A2.y += s2.y;
    }

    float v[10] = { A0.x, A0.y, A0.z, A0.w, A1.x, A1.y, A1.z, A1.w, A2.x, A2.y };
    #pragma unroll
    for (int q = 0; q < 10; q++) {
        v[q] += __shfl_xor(v[q], 1);
        v[q] += __shfl_xor(v[q], 2);
    }

    if (k == 0) {
        float d = dis[n];
        float o = sbo;
        #pragma unroll
        for (int q = 0; q < HG; q++)
            o = fmaf(fmaf(v[q], d, sbc[q]), sWo[q], o);
        out[n] = 1.f / (1.f + __expf(-o));
    }
}

// ================= Fallback path (Round-1 scatter) =================
__global__ __launch_bounds__(256) void edge_mlp_kernel(
    const float* __restrict__ x, const float* __restrict__ token,
    const float* __restrict__ eg, const float* __restrict__ ee,
    const float* __restrict__ gum, const int* __restrict__ eidx,
    const float* __restrict__ W0, const float* __restrict__ b0,
    const float* __restrict__ W1, const float* __restrict__ b1,
    const float* __restrict__ W2, const float* __restrict__ b2,
    const float* __restrict__ W3, const float* __restrict__ b3,
    const float* __restrict__ Wl, const float* __restrict__ bl,
    float* __restrict__ ew_out, float* __restrict__ deg)
{
    __shared__ float sW0[13 * HM];
    __shared__ float sW1[HM * HM];
    __shared__ float sW2[HM * HM];
    __shared__ float sW3f[HM * 2];
    __shared__ float sb0[HM], sb1[HM], sb2[HM], sb3[2];
    __shared__ float sWl, sbl;

    for (int i = threadIdx.x; i < 13 * HM; i += 256) sW0[i] = W0[i];
    for (int i = threadIdx.x; i < HM * HM; i += 256) sW1[i] = W1[i];
    for (int i = threadIdx.x; i < HM * HM; i += 256) sW2[i] = W2[i];
    for (int i = threadIdx.x; i < HM * 2; i += 256) sW3f[i] = W3[i];
    if (threadIdx.x < HM) {
        sb0[threadIdx.x] = b0[threadIdx.x];
        sb1[threadIdx.x] = b1[threadIdx.x];
        sb2[threadIdx.x] = b2[threadIdx.x];
    }
    if (threadIdx.x < 2) sb3[threadIdx.x] = b3[threadIdx.x];
    if (threadIdx.x == 0) { sWl = Wl[0]; sbl = bl[0]; }
    __syncthreads();

    int e = blockIdx.x * 256 + threadIdx.x;
    if (e >= NE) return;
    int s = eidx[e];
    int t = eidx[NE + e];

    float ef[13];
    ef[0] = x[s];
    #pragma unroll
    for (int i = 0; i < 5; i++) ef[1 + i] = token[s * 5 + i];
    ef[6] = x[t];
    #pragma unroll
    for (int i = 0; i < 5; i++) ef[7 + i] = token[t * 5 + i];
    ef[12] = eg[e];

    float h[HM], h2[HM];
    #pragma unroll
    for (int j = 0; j < HM; j++) {
        float a = sb0[j];
        #pragma unroll
        for (int i = 0; i < 13; i++) a = fmaf(ef[i], sW0[i * HM + j], a);
        h[j] = a > 0.f ? a : 0.f;
    }
    #pragma unroll
    for (int j = 0; j < HM; j++) {
        float a = sb1[j];
        #pragma unroll
        for (int i = 0; i < HM; i++) a = fmaf(h[i], sW1[i * HM + j], a);
        h2[j] = a > 0.f ? a : 0.f;
    }
    #pragma unroll
    for (int j = 0; j < HM; j++) {
        float a = sb2[j];
        #pragma unroll
        for (int i = 0; i < HM; i++) a = fmaf(h2[i], sW2[i * HM + j], a);
        h[j] = a > 0.f ? a : 0.f;
    }
    float l0 = sb3[0], l1 = sb3[1];
    #pragma unroll
    for (int i = 0; i < HM; i++) {
        l0 = fmaf(h[i], sW3f[i * 2 + 0], l0);
        l1 = fmaf(h[i], sW3f[i * 2 + 1], l1);
    }
    const float2 g2 = ((const float2*)gum)[e];
    float v0 = l0 + g2.x, v1 = l1 + g2.y;
    float ew = 0.f;
    if (!(v1 > v0)) {
        const float2 ee2 = ((const float2*)ee)[e];
        float z = fmaf(ee2.x, sWl, sbl);
        ew = ee2.y / (1.f + __expf(-z));
    }
    ew_out[e] = ew;
    if (ew != 0.f) atomicAdd(&deg[t], ew);
}

__global__ __launch_bounds__(256) void node_pre_kernel(
    const float* __restrict__ x, const float* __restrict__ token,
    const float* __restrict__ Wc, const float* __restrict__ deg,
    float* __restrict__ xw, float* __restrict__ dis)
{
    __shared__ float sWc[6 * HG];
    if (threadIdx.x < 6 * HG) sWc[threadIdx.x] = Wc[threadIdx.x];
    __syncthreads();
    int n = blockIdx.x * 256 + threadIdx.x;
    if (n >= NN) return;
    float xa[6];
    xa[0] = x[n];
    #pragma unroll
    for (int i = 0; i < 5; i++) xa[1 + i] = token[n * 5 + i];
    #pragma unroll
    for (int k = 0; k < HG; k++) {
        float a = 0.f;
        #pragma unroll
        for (int i = 0; i < 6; i++) a = fmaf(xa[i], sWc[i * HG + k], a);
        xw[n * HG + k] = a;
    }
    dis[n] = rsqrtf(deg[n] + 1.0f);
}

__global__ __launch_bounds__(256) void edge_scatter_kernel(
    const int* __restrict__ eidx, const float* __restrict__ ew,
    const float* __restrict__ dis, const float* __restrict__ xw,
    float* __restrict__ agg)
{
    int e = blockIdx.x * 256 + threadIdx.x;
    if (e >= NE) return;
    float w = ew[e];
    if (w == 0.f) return;
    int s = eidx[e];
    int t = eidx[NE + e];
    float norm = dis[s] * w * dis[t];
    #pragma unroll
    for (int k = 0; k < HG; k++)
        atomicAdd(&agg[t * HG + k], norm * xw[s * HG + k]);
}

__global__ __launch_bounds__(256) void node_out_kernel(
    const float* __restrict__ agg, const float* __restrict__ xw,
    const float* __restrict__ dis, const float* __restrict__ bc,
    const float* __restrict__ Wo, const float* __restrict__ bo,
    float* __restrict__ out)
{
    __shared__ float sbc[HG], sWo[HG], sbo;
    if (threadIdx.x < HG) { sbc[threadIdx.x] = bc[threadIdx.x]; sWo[threadIdx.x] = Wo[threadIdx.x]; }
    if (threadIdx.x == 0) sbo = bo[0];
    __syncthreads();
    int n = blockIdx.x * 256 + threadIdx.x;
    if (n >= NN) return;
    float d = dis[n];
    float self = d * d;
    float acc = sbo;
    #pragma unroll
    for (int k = 0; k < HG; k++) {
        float v = agg[n * HG + k] + xw[n * HG + k] * self + sbc[k];
        acc = fmaf(v, sWo[k], acc);
    }
    out[n] = 1.f / (1.f + __expf(-acc));
}

extern "C" void kernel_launch(void* const* d_in, const int* in_sizes, int n_in,
                              void* d_out, int out_size, void* d_ws, size_t ws_size,
                              hipStream_t stream) {
    const float* x   = (const float*)d_in[0];
    const float* tok = (const float*)d_in[1];
    const float* eg  = (const float*)d_in[2];
    const float* ee  = (const float*)d_in[3];
    const float* gum = (const float*)d_in[4];
    const int*   ei  = (const int*)d_in[5];
    const float* W0  = (const float*)d_in[6];
    const float* b0  = (const float*)d_in[7];
    const float* W1  = (const float*)d_in[8];
    const float* b1  = (const float*)d_in[9];
    const float* W2  = (const float*)d_in[10];
    const float* b2  = (const float*)d_in[11];
    const float* W3  = (const float*)d_in[12];
    const float* b3  = (const float*)d_in[13];
    const float* Wl  = (const float*)d_in[14];
    const float* bl  = (const float*)d_in[15];
    const float* Wc  = (const float*)d_in[16];
    const float* bc  = (const float*)d_in[17];
    const float* Wo  = (const float*)d_in[18];
    const float* bo  = (const float*)d_in[19];
    float* out = (float*)d_out;

    dim3 blk(256);
    dim3 egrid(NE / 256);               // exact: 12500
    dim3 ngrid((NN + 255) / 256);
    dim3 g4grid((NN * 4 + 255) / 256);  // 4 lanes per node

    // New-path ws layout (float offsets)
    size_t off_xall8 = 0;                              // NN*8
    size_t off_xwp   = off_xall8 + (size_t)NN * 8;     // NN*12
    size_t off_slots = off_xwp + (size_t)NN * 12;      // NN*MAXK*2
    size_t off_cnt   = off_slots + (size_t)NN * MAXK * 2; // NN int
    size_t off_novf  = off_cnt + NN;                   // 1 int
    size_t off_dis   = off_novf + 1;                   // NN
    size_t off_ohead = off_dis + NN;                   // NN int
    size_t off_ovfw  = off_ohead + NN;                 // OVF_CAP
    size_t off_ovfs  = off_ovfw + OVF_CAP;             // OVF_CAP int
    size_t off_onxt  = off_ovfs + OVF_CAP;             // OVF_CAP int
    size_t off_w0t   = (off_onxt + OVF_CAP + 15) & ~(size_t)15; // 30*16
    size_t off_w1t   = off_w0t + 30 * 16;              // 30*32
    size_t off_w2t   = off_w1t + 30 * 32;              // 30*32
    size_t need_new  = (off_w2t + 30 * 32) * sizeof(float);

    if (ws_size >= need_new) {
        float*  ws    = (float*)d_ws;
        float*  xall8 = ws + off_xall8;
        float*  xwp   = ws + off_xwp;
        float2* slots = (float2*)(ws + off_slots);
        int*    cnt   = (int*)(ws + off_cnt);
        int*    novf  = (int*)(ws + off_novf);
        float*  dis   = ws + off_dis;
        int*    ohead = (int*)(ws + off_ohead);
        float*  ovf_w = ws + off_ovfw;
        int*    ovf_s = (int*)(ws + off_ovfs);
        int*    onxt  = (int*)(ws + off_onxt);
        float*  W0T   = ws + off_w0t;
        float*  W1T   = ws + off_w1t;
        float*  W2T   = ws + off_w2t;

        hipMemsetAsync(cnt, 0, (size_t)(NN + 1) * sizeof(int), stream);   // cnt + novf
        hipMemsetAsync(ohead, 0xFF, (size_t)NN * sizeof(int), stream);    // ohead = -1

        wtrans_kernel<<<dim3(1), blk, 0, stream>>>(W0, W1, W2, W0T, W1T, W2T);
        pack_kernel<<<ngrid, blk, 0, stream>>>(x, tok, Wc, xall8, xwp);
        edge_mlp7_kernel<<<egrid, blk, 0, stream>>>(xall8, eg, ee, gum, ei,
                                                    W0T, b0, W1T, b1, W2T, b2,
                                                    W3, b3, Wl, bl, slots, cnt,
                                                    ohead, onxt, ovf_w, ovf_s, novf);
        node_deg_kernel<<<ngrid, blk, 0, stream>>>(slots, cnt, ohead, onxt, ovf_w,
                                                   xwp, dis);
        gather_out4_kernel<<<g4grid, blk, 0, stream>>>(slots, cnt, ohead, onxt,
                                                       ovf_w, ovf_s, xwp, dis,
                                                       bc, Wo, bo, out);
    } else {
        // Fallback: Round-1 scatter layout: [ew: NE][deg: NN][agg: NN*HG][xw: NN*HG][dis: NN]
        float* ws  = (float*)d_ws;
        float* ew  = ws;
        float* deg = ew + NE;
        float* agg = deg + NN;
        float* xw  = agg + (size_t)NN * HG;
        float* dis = xw + (size_t)NN * HG;

        hipMemsetAsync(deg, 0, (size_t)(NN + (size_t)NN * HG) * sizeof(float), stream);
        edge_mlp_kernel<<<egrid, blk, 0, stream>>>(x, tok, eg, ee, gum, ei,
                                                   W0, b0, W1, b1, W2, b2, W3, b3,
                                                   Wl, bl, ew, deg);
        node_pre_kernel<<<ngrid, blk, 0, stream>>>(x, tok, Wc, deg, xw, dis);
        edge_scatter_kernel<<<egrid, blk, 0, stream>>>(ei, ew, dis, xw, agg);
        node_out_kernel<<<ngrid, blk, 0, stream>>>(agg, xw, dis, bc, Wo, bo, out);
    }
}